// Round 9
// baseline (182.516 us; speedup 1.0000x reference)
//
#include <hip/hip_runtime.h>

#define TT 200
#define NN 512
#define DD 4
#define HH 64
#define LL 32
#define SB 16                // sequences per chain (fills MFMA M=16)
#define KP 72                // ushort pitch per h row (144B = 9*16B)
#define LOG2E 1.44269504088896340736f

typedef short bf16x8 __attribute__((ext_vector_type(8)));
typedef float f32x4 __attribute__((ext_vector_type(4)));

union U8 { unsigned short s[8]; unsigned u[4]; bf16x8 v; };

// f32 -> (hi, lo) bf16 limbs by truncation: x = hi + lo + err, |err| <= 2^-16 |x|
__device__ __forceinline__ void split2(float x, unsigned short& hi, unsigned short& lo) {
    unsigned u = __float_as_uint(x);
    hi = (unsigned short)(u >> 16);
    float lf = x - __uint_as_float(u & 0xffff0000u);
    lo = (unsigned short)(__float_as_uint(lf) >> 16);
}

__global__ __launch_bounds__(512, 1)
void gru_traj_kernel(const float* __restrict__ xg,    // (B,T,N,D)
                     const float* __restrict__ W_ih,  // (192,4)
                     const float* __restrict__ W_hh,  // (192,64)
                     const float* __restrict__ b_ih,  // (192,)
                     const float* __restrict__ b_hh,  // (192,)
                     const float* __restrict__ W_enc, // (32,64)
                     const float* __restrict__ b_enc, // (32,)
                     float* __restrict__ out)         // (B,N,32)
{
    // two independent chains per block: [chain][buf][seq][unit]
    __shared__ __align__(16) unsigned short hhi[2][2][SB][KP];   // 18.4 KB total limbs
    __shared__ __align__(16) unsigned short hlo[2][2][SB][KP];
    __shared__ __align__(16) float hsf[2][SB][HH + 4];           // f32 h for epilogue

    const int tid  = threadIdx.x;
    const int bid  = blockIdx.x;
    const int b    = bid >> 4;       // 16 blocks per batch (512 seqs / 32)
    const int nblk = bid & 15;

    const int w  = tid >> 6;     // wave 0..7
    const int c  = w >> 2;       // chain 0/1 (waves 0-3 / 4-7 -> same SIMDs, 2 waves each)
    const int wl = w & 3;        // wave-in-chain -> gate tiles for units 16wl..16wl+15
    const int l  = tid & 63;
    const int lr = l & 15;       // A-row / B-col / C-col within tile
    const int lg = l >> 4;       // k-group (A/B), row-group (C)
    const int u  = 16 * wl + lr; // owned unit
    const int n0 = nblk * 32 + c * 16;   // first seq of this chain

    // ---- B fragments: W_hh^T tiles, prescaled (log2e / 2log2e), bf16 hi/lo limbs ----
    const float sc[3] = { LOG2E, LOG2E, 2.0f * LOG2E };
    bf16x8 bh[3][2], bl[3][2];
    #pragma unroll
    for (int i = 0; i < 3; ++i) {
        const int g = i * 64 + u;
        #pragma unroll
        for (int kc = 0; kc < 2; ++kc) {
            const float* p = W_hh + g * HH + kc * 32 + lg * 8;
            U8 uh, ul;
            #pragma unroll
            for (int j = 0; j < 8; ++j) split2(p[j] * sc[i], uh.s[j], ul.s[j]);
            bh[i][kc] = uh.v; bl[i][kc] = ul.v;
        }
    }
    // per-lane gate constants (unit u), prescaled
    float wih[3][4], cb[3];
    #pragma unroll
    for (int i = 0; i < 3; ++i) {
        const int g = i * 64 + u;
        wih[i][0] = W_ih[g * DD + 0] * sc[i]; wih[i][1] = W_ih[g * DD + 1] * sc[i];
        wih[i][2] = W_ih[g * DD + 2] * sc[i]; wih[i][3] = W_ih[g * DD + 3] * sc[i];
        cb[i] = (i < 2) ? (b_ih[g] + b_hh[g]) * sc[i] : b_ih[g] * sc[i];
    }
    const float bn = b_hh[2 * 64 + u] * sc[2];   // n-gate h-part bias (scaled)

    // ---- init: zero both chains' h limb buffers (h0 = 0) ----
    for (int idx = tid; idx < 2 * 2 * SB * KP / 2; idx += 512) {
        reinterpret_cast<unsigned*>(hhi)[idx] = 0u;
        reinterpret_cast<unsigned*>(hlo)[idx] = 0u;
    }
    float hreg[4] = {0.f, 0.f, 0.f, 0.f};   // h[s = lg*4+r][u]

    // ---- x_0 into registers (broadcast across the 16 lanes of each row group) ----
    float4 xc[4];
    #pragma unroll
    for (int r = 0; r < 4; ++r)
        xc[r] = *reinterpret_cast<const float4*>(
            xg + ((size_t)(b * TT) * NN + n0 + lg * 4 + r) * DD);
    __syncthreads();

    #pragma unroll 2
    for (int t = 0; t < TT; ++t) {
        const int cur = t & 1, nxt = cur ^ 1;
        const int tn  = (t + 1 < TT) ? t + 1 : t;

        // prefetch x_{t+1} into registers (latency hidden by one-step lookahead)
        float4 xn[4];
        #pragma unroll
        for (int r = 0; r < 4; ++r)
            xn[r] = *reinterpret_cast<const float4*>(
                xg + ((size_t)(b * TT + tn) * NN + n0 + lg * 4 + r) * DD);

        // ---- A fragments: this chain's h limb loads ----
        bf16x8 ah0 = *reinterpret_cast<const bf16x8*>(&hhi[c][cur][lr][lg * 8]);
        bf16x8 ah1 = *reinterpret_cast<const bf16x8*>(&hhi[c][cur][lr][32 + lg * 8]);
        bf16x8 al0 = *reinterpret_cast<const bf16x8*>(&hlo[c][cur][lr][lg * 8]);
        bf16x8 al1 = *reinterpret_cast<const bf16x8*>(&hlo[c][cur][lr][32 + lg * 8]);

        // ---- gx (f32 VALU, from registers; overlaps MFMA pipe) ----
        float gxv[3][4];
        #pragma unroll
        for (int r = 0; r < 4; ++r) {
            #pragma unroll
            for (int i = 0; i < 3; ++i)
                gxv[i][r] = fmaf(wih[i][0], xc[r].x, fmaf(wih[i][1], xc[r].y,
                            fmaf(wih[i][2], xc[r].z, fmaf(wih[i][3], xc[r].w, cb[i]))));
        }

        // ---- 18 MFMAs: 6 chains (main depth 2, corr depth 4), shared zero C-init ----
        const f32x4 z4 = {0.f, 0.f, 0.f, 0.f};
        f32x4 aR  = __builtin_amdgcn_mfma_f32_16x16x32_bf16(ah0, bh[0][0], z4, 0,0,0);
        f32x4 aZ  = __builtin_amdgcn_mfma_f32_16x16x32_bf16(ah0, bh[1][0], z4, 0,0,0);
        f32x4 aN  = __builtin_amdgcn_mfma_f32_16x16x32_bf16(ah0, bh[2][0], z4, 0,0,0);
        f32x4 aRc = __builtin_amdgcn_mfma_f32_16x16x32_bf16(al0, bh[0][0], z4, 0,0,0);
        f32x4 aZc = __builtin_amdgcn_mfma_f32_16x16x32_bf16(al0, bh[1][0], z4, 0,0,0);
        f32x4 aNc = __builtin_amdgcn_mfma_f32_16x16x32_bf16(al0, bh[2][0], z4, 0,0,0);
        aR  = __builtin_amdgcn_mfma_f32_16x16x32_bf16(ah1, bh[0][1], aR , 0,0,0);
        aZ  = __builtin_amdgcn_mfma_f32_16x16x32_bf16(ah1, bh[1][1], aZ , 0,0,0);
        aN  = __builtin_amdgcn_mfma_f32_16x16x32_bf16(ah1, bh[2][1], aN , 0,0,0);
        aRc = __builtin_amdgcn_mfma_f32_16x16x32_bf16(al1, bh[0][1], aRc, 0,0,0);
        aZc = __builtin_amdgcn_mfma_f32_16x16x32_bf16(al1, bh[1][1], aZc, 0,0,0);
        aNc = __builtin_amdgcn_mfma_f32_16x16x32_bf16(al1, bh[2][1], aNc, 0,0,0);
        aRc = __builtin_amdgcn_mfma_f32_16x16x32_bf16(ah0, bl[0][0], aRc, 0,0,0);
        aZc = __builtin_amdgcn_mfma_f32_16x16x32_bf16(ah0, bl[1][0], aZc, 0,0,0);
        aNc = __builtin_amdgcn_mfma_f32_16x16x32_bf16(ah0, bl[2][0], aNc, 0,0,0);
        aRc = __builtin_amdgcn_mfma_f32_16x16x32_bf16(ah1, bl[0][1], aRc, 0,0,0);
        aZc = __builtin_amdgcn_mfma_f32_16x16x32_bf16(ah1, bl[1][1], aZc, 0,0,0);
        aNc = __builtin_amdgcn_mfma_f32_16x16x32_bf16(ah1, bl[2][1], aNc, 0,0,0);

        // ---- gates (exp2 domain, native transcendentals) + h update ----
        #pragma unroll
        for (int r = 0; r < 4; ++r) {
            const int s = lg * 4 + r;
            float sR = (aR[r] + aRc[r]) + gxv[0][r];
            float sZ = (aZ[r] + aZc[r]) + gxv[1][r];
            float ghn = (aN[r] + aNc[r]) + bn;
            float rg = __builtin_amdgcn_rcpf(1.0f + __builtin_amdgcn_exp2f(-sR));
            float ez = __builtin_amdgcn_exp2f(-sZ);
            float na = fmaf(rg, ghn, gxv[2][r]);
            na = fminf(fmaxf(na, -44.0f), 44.0f);
            float e  = __builtin_amdgcn_exp2f(-na);
            float nn = (1.0f - e) * __builtin_amdgcn_rcpf(1.0f + e);
            float z  = __builtin_amdgcn_rcpf(1.0f + ez);
            float hn = fmaf(z, hreg[r] - nn, nn);       // (1-z)n + z h
            hreg[r] = hn;
            unsigned short hi, lo;
            split2(hn, hi, lo);
            hhi[c][nxt][s][u] = hi;
            hlo[c][nxt][s][u] = lo;
        }
        #pragma unroll
        for (int r = 0; r < 4; ++r) xc[r] = xn[r];
        __syncthreads();   // h_{t+1} limbs visible; buf[cur] free next iteration
    }

    // ---- epilogue: out = h @ W_enc^T + b_enc (1024 outputs, 2 per thread) ----
    #pragma unroll
    for (int r = 0; r < 4; ++r)
        hsf[c][lg * 4 + r][u] = hreg[r];
    __syncthreads();
    for (int o = tid; o < 2 * SB * LL; o += 512) {
        const int c3 = o >> 9, s = (o >> 5) & 15, li = o & 31;
        float a = b_enc[li];
        #pragma unroll
        for (int k = 0; k < HH; ++k)
            a = fmaf(hsf[c3][s][k], W_enc[li * HH + k], a);
        out[((size_t)b * NN + nblk * 32 + c3 * 16 + s) * LL + li] = a;
    }
}

extern "C" void kernel_launch(void* const* d_in, const int* in_sizes, int n_in,
                              void* d_out, int out_size, void* d_ws, size_t ws_size,
                              hipStream_t stream) {
    const float* xg    = (const float*)d_in[0];
    const float* W_ih  = (const float*)d_in[1];
    const float* W_hh  = (const float*)d_in[2];
    const float* b_ih  = (const float*)d_in[3];
    const float* b_hh  = (const float*)d_in[4];
    const float* W_enc = (const float*)d_in[5];
    const float* b_enc = (const float*)d_in[6];
    float* out = (float*)d_out;

    dim3 grid(128), block(512);   // 128 blocks x 2 independent chains -> 2 waves/SIMD
    hipLaunchKernelGGL(gru_traj_kernel, grid, block, 0, stream,
                       xg, W_ih, W_hh, b_ih, b_hh, W_enc, b_enc, out);
}

// Round 10
// 118.518 us; speedup vs baseline: 1.5400x; 1.5400x over previous
//
#include <hip/hip_runtime.h>

#define TT 200
#define NN 512
#define DD 4
#define HH 64
#define LL 32
#define SB 16                // sequences per block (fills MFMA dim)
#define BPB (NN / SB)        // 32 blocks per batch
#define KP 72                // ushort pitch per h row (144B = 9*16B)
#define LOG2E 1.44269504088896340736f

typedef short bf16x8 __attribute__((ext_vector_type(8)));
typedef float f32x4 __attribute__((ext_vector_type(4)));

union U8 { unsigned short s[8]; unsigned u[4]; bf16x8 v; };

// f32 -> (hi, lo) bf16 limbs by truncation: x = hi + lo + err, |err| <= 2^-16 |x|
__device__ __forceinline__ void split2(float x, unsigned short& hi, unsigned short& lo) {
    unsigned u = __float_as_uint(x);
    hi = (unsigned short)(u >> 16);
    float lf = x - __uint_as_float(u & 0xffff0000u);
    lo = (unsigned short)(__float_as_uint(lf) >> 16);
}

__global__ __launch_bounds__(256, 1)
void gru_traj_kernel(const float* __restrict__ xg,    // (B,T,N,D)
                     const float* __restrict__ W_ih,  // (192,4)
                     const float* __restrict__ W_hh,  // (192,64)
                     const float* __restrict__ b_ih,  // (192,)
                     const float* __restrict__ b_hh,  // (192,)
                     const float* __restrict__ W_enc, // (32,64)
                     const float* __restrict__ b_enc, // (32,)
                     float* __restrict__ out)         // (B,N,32)
{
    __shared__ __align__(16) unsigned short hhi[2][SB][KP];   // h hi-limbs (dbuf)
    __shared__ __align__(16) unsigned short hlo[2][SB][KP];   // h lo-limbs
    __shared__ __align__(16) float hsf[SB][HH + 4];           // f32 h for epilogue

    const int tid = threadIdx.x;
    const int bid = blockIdx.x;
    const int b   = bid >> 5;                // bid / BPB
    const int n0  = (bid & (BPB - 1)) * SB;

    const int w  = tid >> 6;     // wave -> unit-group 16w..16w+15 (C tile rows)
    const int l  = tid & 63;
    const int lr = l & 15;       // A-row (W gate-local) / B-col (seq) / C-col (seq)
    const int lg = l >> 4;       // k-group (A/B) and C row-group
    const int u0 = 16 * w + lg * 4;          // first of 4 owned units (C rows)

    const float sc[3] = { LOG2E, LOG2E, 2.0f * LOG2E };

    // ---- A statics: W_hh tiles, A[m=lr][k=kc*32+lg*8+j] = W_hh[i*64+16w+lr][k] ----
    bf16x8 awh[3][2], awl[3][2];
    #pragma unroll
    for (int i = 0; i < 3; ++i) {
        const int g = i * 64 + 16 * w + lr;
        #pragma unroll
        for (int kc = 0; kc < 2; ++kc) {
            const float* p = W_hh + g * HH + kc * 32 + lg * 8;
            U8 uh, ul;
            #pragma unroll
            for (int j = 0; j < 8; ++j) split2(p[j] * sc[i], uh.s[j], ul.s[j]);
            awh[i][kc] = uh.v; awl[i][kc] = ul.v;
        }
    }
    // ---- per-lane gate constants for 4 owned units (g = i*64 + u0 + r) ----
    float wihc[3][4][4], cbrz[2][4], cbx[4], cbh[4];
    #pragma unroll
    for (int i = 0; i < 3; ++i) {
        #pragma unroll
        for (int r = 0; r < 4; ++r) {
            const int g = i * 64 + u0 + r;
            #pragma unroll
            for (int d = 0; d < 4; ++d) wihc[i][r][d] = W_ih[g * DD + d] * sc[i];
            if (i < 2) cbrz[i][r] = (b_ih[g] + b_hh[g]) * sc[i];
            else       { cbx[r] = b_ih[g] * sc[2]; cbh[r] = b_hh[g] * sc[2]; }
        }
    }

    // ---- init: zero h limb buffers (h0 = 0) ----
    for (int idx = tid; idx < 2 * SB * KP / 2; idx += 256) {
        reinterpret_cast<unsigned*>(hhi)[idx] = 0u;
        reinterpret_cast<unsigned*>(hlo)[idx] = 0u;
    }
    float hreg[4] = {0.f, 0.f, 0.f, 0.f};   // h[s = lr][u0 + r]

    // ---- x_0 into registers (lane's seq = n0 + lr) ----
    float4 xc = *reinterpret_cast<const float4*>(
        xg + ((size_t)(b * TT) * NN + n0 + lr) * DD);
    __syncthreads();

    #pragma unroll 2
    for (int t = 0; t < TT; ++t) {
        const int cur = t & 1, nxt = cur ^ 1;
        const int tn  = (t + 1 < TT) ? t + 1 : t;

        // prefetch x_{t+1} (consumed next step; full step covers latency)
        float4 xn = *reinterpret_cast<const float4*>(
            xg + ((size_t)(b * TT + tn) * NN + n0 + lr) * DD);

        // ---- B fragments: h limbs, B[k=kc*32+lg*8+j][n=lr] = h[lr][k] ----
        bf16x8 bh0 = *reinterpret_cast<const bf16x8*>(&hhi[cur][lr][lg * 8]);
        bf16x8 bh1 = *reinterpret_cast<const bf16x8*>(&hhi[cur][lr][32 + lg * 8]);
        bf16x8 bl0 = *reinterpret_cast<const bf16x8*>(&hlo[cur][lr][lg * 8]);
        bf16x8 bl1 = *reinterpret_cast<const bf16x8*>(&hlo[cur][lr][32 + lg * 8]);

        // ---- gx for my (seq lr, 4 units): f32 VALU, overlaps MFMA pipe ----
        float gxv[3][4];
        #pragma unroll
        for (int i = 0; i < 3; ++i) {
            #pragma unroll
            for (int r = 0; r < 4; ++r) {
                const float c0 = (i < 2) ? cbrz[i][r] : cbx[r];
                gxv[i][r] = fmaf(wihc[i][r][0], xc.x, fmaf(wihc[i][r][1], xc.y,
                            fmaf(wihc[i][r][2], xc.z, fmaf(wihc[i][r][3], xc.w, c0))));
            }
        }

        // ---- 18 MFMAs: D[u][s] = W_hh·h^T; 6 chains (main depth 2, corr depth 4) ----
        const f32x4 z4 = {0.f, 0.f, 0.f, 0.f};
        f32x4 aR  = __builtin_amdgcn_mfma_f32_16x16x32_bf16(awh[0][0], bh0, z4, 0,0,0);
        f32x4 aZ  = __builtin_amdgcn_mfma_f32_16x16x32_bf16(awh[1][0], bh0, z4, 0,0,0);
        f32x4 aN  = __builtin_amdgcn_mfma_f32_16x16x32_bf16(awh[2][0], bh0, z4, 0,0,0);
        f32x4 aRc = __builtin_amdgcn_mfma_f32_16x16x32_bf16(awl[0][0], bh0, z4, 0,0,0);
        f32x4 aZc = __builtin_amdgcn_mfma_f32_16x16x32_bf16(awl[1][0], bh0, z4, 0,0,0);
        f32x4 aNc = __builtin_amdgcn_mfma_f32_16x16x32_bf16(awl[2][0], bh0, z4, 0,0,0);
        aR  = __builtin_amdgcn_mfma_f32_16x16x32_bf16(awh[0][1], bh1, aR , 0,0,0);
        aZ  = __builtin_amdgcn_mfma_f32_16x16x32_bf16(awh[1][1], bh1, aZ , 0,0,0);
        aN  = __builtin_amdgcn_mfma_f32_16x16x32_bf16(awh[2][1], bh1, aN , 0,0,0);
        aRc = __builtin_amdgcn_mfma_f32_16x16x32_bf16(awl[0][1], bh1, aRc, 0,0,0);
        aZc = __builtin_amdgcn_mfma_f32_16x16x32_bf16(awl[1][1], bh1, aZc, 0,0,0);
        aNc = __builtin_amdgcn_mfma_f32_16x16x32_bf16(awl[2][1], bh1, aNc, 0,0,0);
        aRc = __builtin_amdgcn_mfma_f32_16x16x32_bf16(awh[0][0], bl0, aRc, 0,0,0);
        aZc = __builtin_amdgcn_mfma_f32_16x16x32_bf16(awh[1][0], bl0, aZc, 0,0,0);
        aNc = __builtin_amdgcn_mfma_f32_16x16x32_bf16(awh[2][0], bl0, aNc, 0,0,0);
        aRc = __builtin_amdgcn_mfma_f32_16x16x32_bf16(awh[0][1], bl1, aRc, 0,0,0);
        aZc = __builtin_amdgcn_mfma_f32_16x16x32_bf16(awh[1][1], bl1, aZc, 0,0,0);
        aNc = __builtin_amdgcn_mfma_f32_16x16x32_bf16(awh[2][1], bl1, aNc, 0,0,0);

        // ---- gates (exp2 domain) + h update; pack contiguous-unit limbs ----
        unsigned short hib[4], lob[4];
        #pragma unroll
        for (int r = 0; r < 4; ++r) {
            float sR  = (aR[r] + aRc[r]) + gxv[0][r];
            float sZ  = (aZ[r] + aZc[r]) + gxv[1][r];
            float ghn = (aN[r] + aNc[r]) + cbh[r];
            float rg = __builtin_amdgcn_rcpf(1.0f + __builtin_amdgcn_exp2f(-sR));
            float ez = __builtin_amdgcn_exp2f(-sZ);
            float na = fmaf(rg, ghn, gxv[2][r]);
            na = fminf(fmaxf(na, -44.0f), 44.0f);
            float e  = __builtin_amdgcn_exp2f(-na);
            float nn = (1.0f - e) * __builtin_amdgcn_rcpf(1.0f + e);
            float z  = __builtin_amdgcn_rcpf(1.0f + ez);
            float hn = fmaf(z, hreg[r] - nn, nn);       // (1-z)n + z h
            hreg[r] = hn;
            split2(hn, hib[r], lob[r]);
        }
        uint2 ph, pl;
        ph.x = (unsigned)hib[0] | ((unsigned)hib[1] << 16);
        ph.y = (unsigned)hib[2] | ((unsigned)hib[3] << 16);
        pl.x = (unsigned)lob[0] | ((unsigned)lob[1] << 16);
        pl.y = (unsigned)lob[2] | ((unsigned)lob[3] << 16);
        *reinterpret_cast<uint2*>(&hhi[nxt][lr][u0]) = ph;   // h[s=lr][u0..u0+3] hi
        *reinterpret_cast<uint2*>(&hlo[nxt][lr][u0]) = pl;   // lo
        xc = xn;
        __syncthreads();   // h_{t+1} limbs visible; buf[cur] free next iteration
    }

    // ---- epilogue: out = h @ W_enc^T + b_enc (512 outputs, strided) ----
    #pragma unroll
    for (int r = 0; r < 4; ++r)
        hsf[lr][u0 + r] = hreg[r];
    __syncthreads();
    for (int o = tid; o < SB * LL; o += 256) {
        const int s = o >> 5, li = o & 31;
        float a = b_enc[li];
        #pragma unroll
        for (int k = 0; k < HH; ++k)
            a = fmaf(hsf[s][k], W_enc[li * HH + k], a);
        out[(bid * SB + s) * LL + li] = a;
    }
}

extern "C" void kernel_launch(void* const* d_in, const int* in_sizes, int n_in,
                              void* d_out, int out_size, void* d_ws, size_t ws_size,
                              hipStream_t stream) {
    const float* xg    = (const float*)d_in[0];
    const float* W_ih  = (const float*)d_in[1];
    const float* W_hh  = (const float*)d_in[2];
    const float* b_ih  = (const float*)d_in[3];
    const float* b_hh  = (const float*)d_in[4];
    const float* W_enc = (const float*)d_in[5];
    const float* b_enc = (const float*)d_in[6];
    float* out = (float*)d_out;

    dim3 grid(8 * BPB), block(256);   // 256 blocks -> exactly 1 block/CU
    hipLaunchKernelGGL(gru_traj_kernel, grid, block, 0, stream,
                       xg, W_ih, W_hh, b_ih, b_hh, W_enc, b_enc, out);
}

// Round 11
// 112.666 us; speedup vs baseline: 1.6200x; 1.0519x over previous
//
#include <hip/hip_runtime.h>

#define TT 200
#define NN 512
#define DD 4
#define HH 64
#define LL 32
#define SB 16                // sequences per block (fills MFMA dim)
#define BPB (NN / SB)        // 32 blocks per batch
#define KP 72                // ushort pitch per h row (144B = 9*16B)
#define LOG2E 1.44269504088896340736f

typedef short bf16x8 __attribute__((ext_vector_type(8)));
typedef float f32x4 __attribute__((ext_vector_type(4)));

union U8 { unsigned short s[8]; unsigned u[4]; bf16x8 v; };

// f32 -> (hi, lo) bf16 limbs by truncation: x = hi + lo + err, |err| <= 2^-16 |x|
__device__ __forceinline__ void split2(float x, unsigned short& hi, unsigned short& lo) {
    unsigned u = __float_as_uint(x);
    hi = (unsigned short)(u >> 16);
    float lf = x - __uint_as_float(u & 0xffff0000u);
    lo = (unsigned short)(__float_as_uint(lf) >> 16);
}

__global__ __launch_bounds__(256, 1)
void gru_traj_kernel(const float* __restrict__ xg,    // (B,T,N,D)
                     const float* __restrict__ W_ih,  // (192,4)
                     const float* __restrict__ W_hh,  // (192,64)
                     const float* __restrict__ b_ih,  // (192,)
                     const float* __restrict__ b_hh,  // (192,)
                     const float* __restrict__ W_enc, // (32,64)
                     const float* __restrict__ b_enc, // (32,)
                     float* __restrict__ out)         // (B,N,32)
{
    __shared__ __align__(16) unsigned short hhi[2][SB][KP];   // h hi-limbs (dbuf)
    __shared__ __align__(16) unsigned short hlo[2][SB][KP];   // h lo-limbs
    __shared__ __align__(16) float hsf[SB][HH + 4];           // f32 h for epilogue

    const int tid = threadIdx.x;
    const int bid = blockIdx.x;
    const int b   = bid >> 5;                // bid / BPB
    const int n0  = (bid & (BPB - 1)) * SB;

    const int w  = tid >> 6;     // wave -> unit-group 16w..16w+15 (C tile rows)
    const int l  = tid & 63;
    const int lr = l & 15;       // A-row (W gate-local) / B-col (seq) / C-col (seq)
    const int lg = l >> 4;       // k-group (A/B) and C row-group
    const int u0 = 16 * w + lg * 4;          // first of 4 owned units (C rows)

    const float sc[3] = { LOG2E, LOG2E, 2.0f * LOG2E };

    // ---- A statics: W_hh hi-limbs only (W-lo product dropped; error budget in theory) ----
    bf16x8 awh[3][2];
    #pragma unroll
    for (int i = 0; i < 3; ++i) {
        const int g = i * 64 + 16 * w + lr;
        #pragma unroll
        for (int kc = 0; kc < 2; ++kc) {
            const float* p = W_hh + g * HH + kc * 32 + lg * 8;
            U8 uh;
            #pragma unroll
            for (int j = 0; j < 8; ++j) {
                unsigned short hi, lo;
                split2(p[j] * sc[i], hi, lo);
                uh.s[j] = hi; (void)lo;
            }
            awh[i][kc] = uh.v;
        }
    }
    // ---- per-lane gate constants for 4 owned units (g = i*64 + u0 + r) ----
    float wihc[3][4][4], cbrz[2][4], cbx[4], cbh[4];
    #pragma unroll
    for (int i = 0; i < 3; ++i) {
        #pragma unroll
        for (int r = 0; r < 4; ++r) {
            const int g = i * 64 + u0 + r;
            #pragma unroll
            for (int d = 0; d < 4; ++d) wihc[i][r][d] = W_ih[g * DD + d] * sc[i];
            if (i < 2) cbrz[i][r] = (b_ih[g] + b_hh[g]) * sc[i];
            else       { cbx[r] = b_ih[g] * sc[2]; cbh[r] = b_hh[g] * sc[2]; }
        }
    }

    // ---- init: zero h limb buffers (h0 = 0) ----
    for (int idx = tid; idx < 2 * SB * KP / 2; idx += 256) {
        reinterpret_cast<unsigned*>(hhi)[idx] = 0u;
        reinterpret_cast<unsigned*>(hlo)[idx] = 0u;
    }
    float hreg[4] = {0.f, 0.f, 0.f, 0.f};   // h[s = lr][u0 + r]

    // ---- x_0 into registers (lane's seq = n0 + lr) ----
    float4 xc = *reinterpret_cast<const float4*>(
        xg + ((size_t)(b * TT) * NN + n0 + lr) * DD);
    __syncthreads();

    #pragma unroll 2
    for (int t = 0; t < TT; ++t) {
        const int cur = t & 1, nxt = cur ^ 1;
        const int tn  = (t + 1 < TT) ? t + 1 : t;

        // prefetch x_{t+1} (consumed next step; full step covers latency)
        float4 xn = *reinterpret_cast<const float4*>(
            xg + ((size_t)(b * TT + tn) * NN + n0 + lr) * DD);

        // ---- B fragments: h limbs, B[k=kc*32+lg*8+j][n=lr] = h[lr][k] ----
        bf16x8 bh0 = *reinterpret_cast<const bf16x8*>(&hhi[cur][lr][lg * 8]);
        bf16x8 bh1 = *reinterpret_cast<const bf16x8*>(&hhi[cur][lr][32 + lg * 8]);
        bf16x8 bl0 = *reinterpret_cast<const bf16x8*>(&hlo[cur][lr][lg * 8]);
        bf16x8 bl1 = *reinterpret_cast<const bf16x8*>(&hlo[cur][lr][32 + lg * 8]);

        // ---- gx for my (seq lr, 4 units): f32 VALU, overlaps MFMA pipe ----
        float gxv[3][4];
        #pragma unroll
        for (int i = 0; i < 3; ++i) {
            #pragma unroll
            for (int r = 0; r < 4; ++r) {
                const float c0 = (i < 2) ? cbrz[i][r] : cbx[r];
                gxv[i][r] = fmaf(wihc[i][r][0], xc.x, fmaf(wihc[i][r][1], xc.y,
                            fmaf(wihc[i][r][2], xc.z, fmaf(wihc[i][r][3], xc.w, c0))));
            }
        }

        // ---- 12 MFMAs: 6 independent depth-2 chains (Whi*h_hi and Whi*h_lo) ----
        const f32x4 z4 = {0.f, 0.f, 0.f, 0.f};
        f32x4 aR  = __builtin_amdgcn_mfma_f32_16x16x32_bf16(awh[0][0], bh0, z4, 0,0,0);
        f32x4 aZ  = __builtin_amdgcn_mfma_f32_16x16x32_bf16(awh[1][0], bh0, z4, 0,0,0);
        f32x4 aN  = __builtin_amdgcn_mfma_f32_16x16x32_bf16(awh[2][0], bh0, z4, 0,0,0);
        f32x4 aRc = __builtin_amdgcn_mfma_f32_16x16x32_bf16(awh[0][0], bl0, z4, 0,0,0);
        f32x4 aZc = __builtin_amdgcn_mfma_f32_16x16x32_bf16(awh[1][0], bl0, z4, 0,0,0);
        f32x4 aNc = __builtin_amdgcn_mfma_f32_16x16x32_bf16(awh[2][0], bl0, z4, 0,0,0);
        aR  = __builtin_amdgcn_mfma_f32_16x16x32_bf16(awh[0][1], bh1, aR , 0,0,0);
        aZ  = __builtin_amdgcn_mfma_f32_16x16x32_bf16(awh[1][1], bh1, aZ , 0,0,0);
        aN  = __builtin_amdgcn_mfma_f32_16x16x32_bf16(awh[2][1], bh1, aN , 0,0,0);
        aRc = __builtin_amdgcn_mfma_f32_16x16x32_bf16(awh[0][1], bl1, aRc, 0,0,0);
        aZc = __builtin_amdgcn_mfma_f32_16x16x32_bf16(awh[1][1], bl1, aZc, 0,0,0);
        aNc = __builtin_amdgcn_mfma_f32_16x16x32_bf16(awh[2][1], bl1, aNc, 0,0,0);

        // ---- gates (exp2 domain; no clamp — |na| <= 2log2e*(8+2.9) < 32, exp2 safe) ----
        unsigned short hib[4], lob[4];
        #pragma unroll
        for (int r = 0; r < 4; ++r) {
            float sR  = (aR[r] + aRc[r]) + gxv[0][r];
            float sZ  = (aZ[r] + aZc[r]) + gxv[1][r];
            float ghn = (aN[r] + aNc[r]) + cbh[r];
            float rg = __builtin_amdgcn_rcpf(1.0f + __builtin_amdgcn_exp2f(-sR));
            float ez = __builtin_amdgcn_exp2f(-sZ);
            float na = fmaf(rg, ghn, gxv[2][r]);
            float e  = __builtin_amdgcn_exp2f(-na);
            float nn = fmaf(2.0f, __builtin_amdgcn_rcpf(1.0f + e), -1.0f);  // tanh
            float z  = __builtin_amdgcn_rcpf(1.0f + ez);
            float hn = fmaf(z, hreg[r] - nn, nn);       // (1-z)n + z h
            hreg[r] = hn;
            split2(hn, hib[r], lob[r]);
        }
        uint2 ph, pl;
        ph.x = (unsigned)hib[0] | ((unsigned)hib[1] << 16);
        ph.y = (unsigned)hib[2] | ((unsigned)hib[3] << 16);
        pl.x = (unsigned)lob[0] | ((unsigned)lob[1] << 16);
        pl.y = (unsigned)lob[2] | ((unsigned)lob[3] << 16);
        *reinterpret_cast<uint2*>(&hhi[nxt][lr][u0]) = ph;   // h[s=lr][u0..u0+3] hi
        *reinterpret_cast<uint2*>(&hlo[nxt][lr][u0]) = pl;   // lo
        xc = xn;
        __syncthreads();   // h_{t+1} limbs visible; buf[cur] free next iteration
    }

    // ---- epilogue: out = h @ W_enc^T + b_enc (512 outputs, strided) ----
    #pragma unroll
    for (int r = 0; r < 4; ++r)
        hsf[lr][u0 + r] = hreg[r];
    __syncthreads();
    for (int o = tid; o < SB * LL; o += 256) {
        const int s = o >> 5, li = o & 31;
        float a = b_enc[li];
        #pragma unroll
        for (int k = 0; k < HH; ++k)
            a = fmaf(hsf[s][k], W_enc[li * HH + k], a);
        out[(bid * SB + s) * LL + li] = a;
    }
}

extern "C" void kernel_launch(void* const* d_in, const int* in_sizes, int n_in,
                              void* d_out, int out_size, void* d_ws, size_t ws_size,
                              hipStream_t stream) {
    const float* xg    = (const float*)d_in[0];
    const float* W_ih  = (const float*)d_in[1];
    const float* W_hh  = (const float*)d_in[2];
    const float* b_ih  = (const float*)d_in[3];
    const float* b_hh  = (const float*)d_in[4];
    const float* W_enc = (const float*)d_in[5];
    const float* b_enc = (const float*)d_in[6];
    float* out = (float*)d_out;

    dim3 grid(8 * BPB), block(256);   // 256 blocks -> exactly 1 block/CU
    hipLaunchKernelGGL(gru_traj_kernel, grid, block, 0, stream,
                       xg, W_ih, W_hh, b_ih, b_hh, W_enc, b_enc, out);
}